// Round 10
// baseline (467.211 us; speedup 1.0000x reference)
//
#include <hip/hip_runtime.h>
#include <hip/hip_fp16.h>

// GNN link predict: 2-layer GAT (H=2, C=64, HC=128) + factored MLP decoder.
// GEMMs via v_mfma_f32_16x16x32_f16 (fp16 in, fp32 accum) with fused attn coefs.
// fp16 gather tables; CSR built once; XCD-partitioned hist+scatter;
// v_fma_mix_f32 for fp16-gather FMAs (exact f16->f32 cvt + fp32 fma, 1 instr).

typedef _Float16 f16x8 __attribute__((ext_vector_type(8)));
typedef float f32x4 __attribute__((ext_vector_type(4)));

__device__ __forceinline__ float rl_f(float v, int lane) {
    return __int_as_float(__builtin_amdgcn_readlane(__float_as_int(v), lane));
}

// acc += (f32)lo_half(hv) * e   /   acc += (f32)hi_half(hv) * e
__device__ __forceinline__ void fma_mix_lo(float& acc, unsigned hv, float e) {
    asm("v_fma_mix_f32 %0, %1, %2, %0 op_sel_hi:[1,0,0]"
        : "+v"(acc) : "v"(hv), "v"(e));
}
__device__ __forceinline__ void fma_mix_hi(float& acc, unsigned hv, float e) {
    asm("v_fma_mix_f32 %0, %1, %2, %0 op_sel:[1,0,0] op_sel_hi:[1,0,0]"
        : "+v"(acc) : "v"(hv), "v"(e));
}

// ---------------- MFMA GEMM: Y16[nrows,128](fp16) = X[nrows,128]fp32 @ W[128,128]fp32 ----------------
#define WT_LD 136
__global__ __launch_bounds__(256, 3) void gemm_mfma(
    const float* __restrict__ X, const float* __restrict__ W,
    _Float16* __restrict__ Y, int nrows,
    const float* __restrict__ att_s, const float* __restrict__ att_d,
    float2* __restrict__ as_out, float2* __restrict__ ad_out)
{
    __shared__ _Float16 WT[128 * WT_LD];
    __shared__ _Float16 At[64 * WT_LD];
    const int t = threadIdx.x;
    const int lane = t & 63;
    const int wid = t >> 6;

    // stage W^T as fp16: WT[n][k] = W[k][n]
    for (int i = t; i < 128 * 32; i += 256) {
        const int k = i >> 5;
        const int n4 = (i & 31) * 4;
        const float4 wv = *reinterpret_cast<const float4*>(&W[k * 128 + n4]);
        WT[(n4 + 0) * WT_LD + k] = (_Float16)wv.x;
        WT[(n4 + 1) * WT_LD + k] = (_Float16)wv.y;
        WT[(n4 + 2) * WT_LD + k] = (_Float16)wv.z;
        WT[(n4 + 3) * WT_LD + k] = (_Float16)wv.w;
    }

    const int am = lane & 15, ag = lane >> 4;

    float asv[8], adv[8];
    if (as_out) {
#pragma unroll
        for (int n0 = 0; n0 < 8; ++n0) {
            asv[n0] = att_s[n0 * 16 + am];
            adv[n0] = att_d[n0 * 16 + am];
        }
    }

    const int ntiles = (nrows + 63) >> 6;
    for (int tile = blockIdx.x; tile < ntiles; tile += gridDim.x) {
        const int rbase = tile * 64;
        __syncthreads();
        {
            const int r = t >> 2;
            const int c0 = (t & 3) * 32;      // halfs
            const int gr = rbase + r;
            _Float16 tmp[32];
            if (gr < nrows) {
                const float* src = X + (size_t)gr * 128 + c0;
#pragma unroll
                for (int q = 0; q < 8; ++q) {
                    const float4 v = *reinterpret_cast<const float4*>(src + q * 4);
                    tmp[q * 4 + 0] = (_Float16)v.x; tmp[q * 4 + 1] = (_Float16)v.y;
                    tmp[q * 4 + 2] = (_Float16)v.z; tmp[q * 4 + 3] = (_Float16)v.w;
                }
            } else {
#pragma unroll
                for (int q = 0; q < 32; ++q) tmp[q] = (_Float16)0.f;
            }
#pragma unroll
            for (int q = 0; q < 4; ++q)
                *reinterpret_cast<f16x8*>(&At[r * WT_LD + c0 + q * 8]) =
                    *reinterpret_cast<const f16x8*>(&tmp[q * 8]);
        }
        __syncthreads();

        const int srow = wid * 16;
        f16x8 a[4];
#pragma unroll
        for (int kb = 0; kb < 4; ++kb)
            a[kb] = *reinterpret_cast<const f16x8*>(
                &At[(srow + am) * WT_LD + kb * 32 + ag * 8]);

        f32x4 acc[8];
#pragma unroll
        for (int n0 = 0; n0 < 8; ++n0) {
            f32x4 c = {0.f, 0.f, 0.f, 0.f};
#pragma unroll
            for (int kb = 0; kb < 4; ++kb) {
                const f16x8 b = *reinterpret_cast<const f16x8*>(
                    &WT[(n0 * 16 + am) * WT_LD + kb * 32 + ag * 8]);
                c = __builtin_amdgcn_mfma_f32_16x16x32_f16(a[kb], b, c, 0, 0, 0);
            }
            acc[n0] = c;
        }

        const int growbase = rbase + srow + ag * 4;

#pragma unroll
        for (int j = 0; j < 4; ++j) {
            const int grow = growbase + j;
            if (grow < nrows) {
#pragma unroll
                for (int n0 = 0; n0 < 8; ++n0)
                    Y[(size_t)grow * 128 + n0 * 16 + am] = (_Float16)acc[n0][j];
            }
        }

        if (as_out) {
#pragma unroll
            for (int j = 0; j < 4; ++j) {
                float s0 = 0.f, s1 = 0.f, d0 = 0.f, d1 = 0.f;
#pragma unroll
                for (int n0 = 0; n0 < 4; ++n0) {
                    s0 = fmaf(acc[n0][j], asv[n0], s0);
                    d0 = fmaf(acc[n0][j], adv[n0], d0);
                }
#pragma unroll
                for (int n0 = 4; n0 < 8; ++n0) {
                    s1 = fmaf(acc[n0][j], asv[n0], s1);
                    d1 = fmaf(acc[n0][j], adv[n0], d1);
                }
#pragma unroll
                for (int off = 1; off < 16; off <<= 1) {
                    s0 += __shfl_xor(s0, off, 64); s1 += __shfl_xor(s1, off, 64);
                    d0 += __shfl_xor(d0, off, 64); d1 += __shfl_xor(d1, off, 64);
                }
                const int grow = growbase + j;
                if (am == 0 && grow < nrows) {
                    as_out[grow] = make_float2(s0, s1);
                    ad_out[grow] = make_float2(d0, d1);
                }
            }
        }
    }
}

// ---------------- CSR build ----------------
__global__ __launch_bounds__(256) void init_counts_k(int* __restrict__ counts, int N)
{
    const int i = blockIdx.x * blockDim.x + threadIdx.x;
    if (i < N) counts[i] = 1;   // self-loop pre-counted
}

// XCD-partitioned histogram: partition p = blockIdx&7 owns dst in [p*npp,(p+1)*npp)
// -> atomics stay in one XCD's L2 (no cross-XCD coherence ping-pong).
__global__ __launch_bounds__(256) void hist_xcd_k(
    const int* __restrict__ edst, int E, int* __restrict__ counts, int npp)
{
    const int part = blockIdx.x & 7;
    const int lo = part * npp;
    const int hiN = lo + npp;
    const int bi = blockIdx.x >> 3;
    const int stride = (gridDim.x >> 3) * blockDim.x;
    for (int e = bi * blockDim.x + threadIdx.x; e < E; e += stride) {
        const int d = edst[e];
        if (d >= lo && d < hiN) atomicAdd(&counts[d], 1);
    }
}

__global__ __launch_bounds__(256) void scan_phase1(
    const int* __restrict__ counts, int* __restrict__ blockSums, int N)
{
    __shared__ int wsum[4];
    const int b = blockIdx.x, t = threadIdx.x;
    const int base = b * 1024 + t * 4;
    int s = 0;
    if (base + 3 < N) {
        const int4 c = *reinterpret_cast<const int4*>(&counts[base]);
        s = c.x + c.y + c.z + c.w;
    } else {
#pragma unroll
        for (int k = 0; k < 4; ++k) if (base + k < N) s += counts[base + k];
    }
#pragma unroll
    for (int off = 32; off; off >>= 1) s += __shfl_xor(s, off, 64);
    if ((t & 63) == 0) wsum[t >> 6] = s;
    __syncthreads();
    if (t == 0) blockSums[b] = wsum[0] + wsum[1] + wsum[2] + wsum[3];
}

__global__ __launch_bounds__(256) void scan_phase2(
    int* __restrict__ blockSums, int nb, int* __restrict__ row_ptr, int N)
{
    __shared__ int wsum[4];
    __shared__ int carry_sh;
    const int t = threadIdx.x;
    if (t == 0) carry_sh = 0;
    __syncthreads();
    for (int base = 0; base < nb; base += 256) {
        const int i = base + t;
        const int v = (i < nb) ? blockSums[i] : 0;
        int x = v;
#pragma unroll
        for (int off = 1; off < 64; off <<= 1) {
            const int y = __shfl_up(x, off, 64);
            if ((t & 63) >= off) x += y;
        }
        if ((t & 63) == 63) wsum[t >> 6] = x;
        __syncthreads();
        int woff = 0;
        for (int w = 0; w < (t >> 6); ++w) woff += wsum[w];
        const int carry = carry_sh;
        if (i < nb) blockSums[i] = carry + woff + x - v;
        __syncthreads();
        if (t == 255) carry_sh = carry + woff + x;
        __syncthreads();
    }
    if (t == 0) row_ptr[N] = carry_sh;
}

__global__ __launch_bounds__(256) void scan_phase3(
    const int* __restrict__ counts, const int* __restrict__ blockSums,
    int* __restrict__ row_ptr, int N)
{
    __shared__ int wsum[4];
    const int b = blockIdx.x, t = threadIdx.x;
    const int base = b * 1024 + t * 4;
    int v0 = 0, v1 = 0, v2 = 0, v3 = 0;
    if (base + 3 < N) {
        const int4 c = *reinterpret_cast<const int4*>(&counts[base]);
        v0 = c.x; v1 = c.y; v2 = c.z; v3 = c.w;
    } else {
        if (base + 0 < N) v0 = counts[base + 0];
        if (base + 1 < N) v1 = counts[base + 1];
        if (base + 2 < N) v2 = counts[base + 2];
        if (base + 3 < N) v3 = counts[base + 3];
    }
    const int tsum = v0 + v1 + v2 + v3;
    int x = tsum;
#pragma unroll
    for (int off = 1; off < 64; off <<= 1) {
        const int y = __shfl_up(x, off, 64);
        if ((t & 63) >= off) x += y;
    }
    if ((t & 63) == 63) wsum[t >> 6] = x;
    __syncthreads();
    int woff = 0;
    for (int w = 0; w < (t >> 6); ++w) woff += wsum[w];
    int excl = blockSums[b] + woff + x - tsum;
    if (base + 0 < N) row_ptr[base + 0] = excl;
    if (base + 1 < N) row_ptr[base + 1] = excl + v0;
    if (base + 2 < N) row_ptr[base + 2] = excl + v0 + v1;
    if (base + 3 < N) row_ptr[base + 3] = excl + v0 + v1 + v2;
}

__global__ __launch_bounds__(256) void init_cursor_k(
    const int* __restrict__ row_ptr, int* __restrict__ cursor,
    int* __restrict__ csr_src, int N)
{
    const int i = blockIdx.x * blockDim.x + threadIdx.x;
    if (i < N) {
        const int p = row_ptr[i];
        csr_src[p] = i;
        cursor[i] = p + 1;
    }
}

__global__ __launch_bounds__(256) void scatter_xcd_k(
    const int* __restrict__ esrc, const int* __restrict__ edst, int E,
    int* __restrict__ cursor, int* __restrict__ csr_src, int npp)
{
    const int part = blockIdx.x & 7;
    const int lo = part * npp;
    const int hiN = lo + npp;
    const int bi = blockIdx.x >> 3;
    const int stride = (gridDim.x >> 3) * blockDim.x;
    for (int e = bi * blockDim.x + threadIdx.x; e < E; e += stride) {
        const int d = edst[e];
        if (d >= lo && d < hiN) {
            const int pos = atomicAdd(&cursor[d], 1);
            csr_src[pos] = esrc[e];
        }
    }
}

// ---------------- CSR aggregation: one wave per node, fp16 gather, fma_mix ----------------
__global__ __launch_bounds__(256) void csr_aggregate(
    const int* __restrict__ row_ptr, const int* __restrict__ csr_src,
    const unsigned* __restrict__ h2u, const float2* __restrict__ as_,
    const float2* __restrict__ ad_, const float* __restrict__ bias,
    float* __restrict__ out, int N, int do_relu)
{
    const int lane = threadIdx.x & 63;
    const int node = (blockIdx.x * blockDim.x + threadIdx.x) >> 6;
    if (node >= N) return;

    const int start = row_ptr[node];
    const int end   = row_ptr[node + 1];
    const float2 ad = ad_[node];
    const bool hi = lane >= 32;

    float den0 = 0.f, den1 = 0.f;
    float accx = 0.f, accy = 0.f;

    for (int base = start; base < end; base += 64) {
        const int cnt = min(64, end - base);
        float ex0 = 0.f, ex1 = 0.f;
        int s = 0;
        if (lane < cnt) {
            s = csr_src[base + lane];
            const float2 as = as_[s];
            float e0 = as.x + ad.x; e0 = fmaxf(e0, 0.2f * e0);   // leaky relu
            float e1 = as.y + ad.y; e1 = fmaxf(e1, 0.2f * e1);
            ex0 = __expf(e0); ex1 = __expf(e1);
            den0 += ex0; den1 += ex1;
        }
        int j = 0;
        for (; j + 8 <= cnt; j += 8) {
            unsigned idx[8];
            float ej[8];
            unsigned hv[8];
#pragma unroll
            for (int q = 0; q < 8; ++q) {
                idx[q] = (unsigned)(__builtin_amdgcn_readlane(s, j + q) * 64 + lane);
                ej[q] = hi ? rl_f(ex1, j + q) : rl_f(ex0, j + q);
            }
#pragma unroll
            for (int q = 0; q < 8; ++q)
                hv[q] = h2u[idx[q]];
#pragma unroll
            for (int q = 0; q < 8; ++q) {
                fma_mix_lo(accx, hv[q], ej[q]);
                fma_mix_hi(accy, hv[q], ej[q]);
            }
        }
        for (; j < cnt; ++j) {
            const unsigned idx = (unsigned)(__builtin_amdgcn_readlane(s, j) * 64 + lane);
            const float e = hi ? rl_f(ex1, j) : rl_f(ex0, j);
            const unsigned hv = h2u[idx];
            fma_mix_lo(accx, hv, e);
            fma_mix_hi(accy, hv, e);
        }
    }

#pragma unroll
    for (int off = 32; off; off >>= 1) {
        den0 += __shfl_xor(den0, off, 64);
        den1 += __shfl_xor(den1, off, 64);
    }
    const float rd = 1.f / (hi ? den1 : den0);
    const float2 bv = ((const float2*)bias)[lane];
    float vx = fmaf(accx, rd, bv.x);
    float vy = fmaf(accy, rd, bv.y);
    if (do_relu) { vx = fmaxf(vx, 0.f); vy = fmaxf(vy, 0.f); }
    ((float2*)out)[(size_t)node * 64 + lane] = make_float2(vx, vy);
}

// ---------------- build rearranged decoder weight: Wuv[128][128] ----------------
__global__ void build_wuv(const float* __restrict__ lin1_w, float* __restrict__ Wuv)
{
    const int i = blockIdx.x * blockDim.x + threadIdx.x;
    if (i >= 128 * 128) return;
    const int k = i >> 7, j = i & 127;
    Wuv[i] = (j < 64) ? lin1_w[k * 64 + j] : lin1_w[(128 + k) * 64 + (j - 64)];
}

// ---------------- decoder: one wave per label edge (fp16 uv, fma_mix) ----------------
__global__ __launch_bounds__(256) void decode_k(
    const int* __restrict__ eli, int L_, const unsigned short* __restrict__ uv,
    const float* __restrict__ lin1_b, const float* __restrict__ lin2_w,
    const float* __restrict__ lin2_b, float* __restrict__ out)
{
    const int lane = threadIdx.x & 63;
    const int wstride = (gridDim.x * blockDim.x) >> 6;
    const float bl = lin1_b[lane];
    const float wl = lin2_w[lane];
    for (int wid = (blockIdx.x * blockDim.x + threadIdx.x) >> 6; wid < L_; wid += wstride) {
        const int a = eli[wid], b = eli[L_ + wid];
        const unsigned ua = uv[(unsigned)(a * 128 + lane)];        // f16 in lo bits
        const unsigned ub = uv[(unsigned)(b * 128 + 64 + lane)];
        float x = bl;
        asm("v_fma_mix_f32 %0, %1, 1.0, %0 op_sel_hi:[1,0,0]" : "+v"(x) : "v"(ua));
        asm("v_fma_mix_f32 %0, %1, 1.0, %0 op_sel_hi:[1,0,0]" : "+v"(x) : "v"(ub));
        x = x > 0.f ? x : 0.f;
        float p = x * wl;
#pragma unroll
        for (int off = 32; off; off >>= 1) p += __shfl_xor(p, off, 64);
        if (lane == 0) out[wid] = p + lin2_b[0];
    }
}

extern "C" void kernel_launch(void* const* d_in, const int* in_sizes, int n_in,
                              void* d_out, int out_size, void* d_ws, size_t ws_size,
                              hipStream_t stream)
{
    const float* x     = (const float*)d_in[0];
    const int*   ei    = (const int*)d_in[1];
    const int*   eli   = (const int*)d_in[2];
    const float* W1    = (const float*)d_in[3];
    const float* atts1 = (const float*)d_in[4];
    const float* attd1 = (const float*)d_in[5];
    const float* bias1 = (const float*)d_in[6];
    const float* W2    = (const float*)d_in[7];
    const float* atts2 = (const float*)d_in[8];
    const float* attd2 = (const float*)d_in[9];
    const float* bias2 = (const float*)d_in[10];
    const float* lin1w = (const float*)d_in[11];
    const float* lin1b = (const float*)d_in[12];
    const float* lin2w = (const float*)d_in[13];
    const float* lin2b = (const float*)d_in[14];
    float* out = (float*)d_out;

    const int N = in_sizes[0] / 128;
    const int E = in_sizes[1] / 2;
    const int L = in_sizes[2] / 2;

    float* ws   = (float*)d_ws;
    __half2* h16 = (__half2*)ws;                  // N*64 half2 = N*128 halfs
    float* x2z  = ws + (size_t)N * 64;            // N*128
    float* a_s  = x2z + (size_t)N * 128;          // N*2
    float* a_d  = a_s + (size_t)N * 2;            // N*2
    float* Wuv  = a_d + (size_t)N * 2;            // 128*128
    int* row_ptr = (int*)(Wuv + 128 * 128);       // N+1 (padded to N+4)
    int* counts  = row_ptr + (N + 4);             // N (16B-aligned)
    int* cursor  = counts + N;                    // N
    int* csr_src = cursor + N;                    // E+N
    int* blockSums = csr_src + (E + N);           // nb

    const int nBlocks256 = (N + 255) / 256;
    const int nb = (N + 1023) / 1024;
    const int npp = (N + 7) / 8;
    const int ntiles = (N + 63) / 64;
    const int gemmGrid = ntiles < 768 ? ntiles : 768;

    // ---- CSR build (once, reused by both layers) ----
    init_counts_k<<<nBlocks256, 256, 0, stream>>>(counts, N);
    hist_xcd_k<<<2048, 256, 0, stream>>>(ei + E, E, counts, npp);
    scan_phase1<<<nb, 256, 0, stream>>>(counts, blockSums, N);
    scan_phase2<<<1, 256, 0, stream>>>(blockSums, nb, row_ptr, N);
    scan_phase3<<<nb, 256, 0, stream>>>(counts, blockSums, row_ptr, N);
    init_cursor_k<<<nBlocks256, 256, 0, stream>>>(row_ptr, cursor, csr_src, N);
    scatter_xcd_k<<<2048, 256, 0, stream>>>(ei, ei + E, E, cursor, csr_src, npp);

    for (int layer = 0; layer < 2; ++layer) {
        const float* xin  = (layer == 0) ? x : x2z;
        const float* W    = (layer == 0) ? W1 : W2;
        const float* as_w = (layer == 0) ? atts1 : atts2;
        const float* ad_w = (layer == 0) ? attd1 : attd2;
        const float* bs   = (layer == 0) ? bias1 : bias2;

        gemm_mfma<<<gemmGrid, 256, 0, stream>>>(xin, W, (_Float16*)h16, N, as_w, ad_w,
                                                (float2*)a_s, (float2*)a_d);
        csr_aggregate<<<(N + 3) / 4, 256, 0, stream>>>(row_ptr, csr_src,
                                                       (const unsigned*)h16,
                                                       (const float2*)a_s, (const float2*)a_d,
                                                       bs, x2z, N, (layer == 0) ? 1 : 0);
    }

    build_wuv<<<64, 256, 0, stream>>>(lin1w, Wuv);
    gemm_mfma<<<gemmGrid, 256, 0, stream>>>(x2z, Wuv, (_Float16*)h16, N,
                                            nullptr, nullptr, nullptr, nullptr);
    decode_k<<<8192, 256, 0, stream>>>(eli, L, (const unsigned short*)h16,
                                       lin1b, lin2w, lin2b, out);
}

// Round 11
// 437.977 us; speedup vs baseline: 1.0667x; 1.0667x over previous
//
#include <hip/hip_runtime.h>
#include <hip/hip_fp16.h>

// GNN link predict: 2-layer GAT (H=2, C=64, HC=128) + factored MLP decoder.
// GEMMs via v_mfma_f32_16x16x32_f16 (fp16 in, fp32 accum) with fused attn coefs.
// fp16 gather tables; CSR built once; XCD-partitioned hist+scatter.
// csr_aggregate: 2 edges/wave, 8B/lane gathers (half the vmem instructions).

typedef _Float16 f16x8 __attribute__((ext_vector_type(8)));
typedef float f32x4 __attribute__((ext_vector_type(4)));

__device__ __forceinline__ float rl_f(float v, int lane) {
    return __int_as_float(__builtin_amdgcn_readlane(__float_as_int(v), lane));
}

// acc += (f32)lo_half(hv) * e   /   acc += (f32)hi_half(hv) * e   (exact cvt + fp32 fma)
__device__ __forceinline__ void fma_mix_lo(float& acc, unsigned hv, float e) {
    asm("v_fma_mix_f32 %0, %1, %2, %0 op_sel_hi:[1,0,0]"
        : "+v"(acc) : "v"(hv), "v"(e));
}
__device__ __forceinline__ void fma_mix_hi(float& acc, unsigned hv, float e) {
    asm("v_fma_mix_f32 %0, %1, %2, %0 op_sel:[1,0,0] op_sel_hi:[1,0,0]"
        : "+v"(acc) : "v"(hv), "v"(e));
}

// ---------------- MFMA GEMM: Y16[nrows,128](fp16) = X[nrows,128]fp32 @ W[128,128]fp32 ----------------
#define WT_LD 136
__global__ __launch_bounds__(256, 3) void gemm_mfma(
    const float* __restrict__ X, const float* __restrict__ W,
    _Float16* __restrict__ Y, int nrows,
    const float* __restrict__ att_s, const float* __restrict__ att_d,
    float2* __restrict__ as_out, float2* __restrict__ ad_out)
{
    __shared__ _Float16 WT[128 * WT_LD];
    __shared__ _Float16 At[64 * WT_LD];
    const int t = threadIdx.x;
    const int lane = t & 63;
    const int wid = t >> 6;

    for (int i = t; i < 128 * 32; i += 256) {
        const int k = i >> 5;
        const int n4 = (i & 31) * 4;
        const float4 wv = *reinterpret_cast<const float4*>(&W[k * 128 + n4]);
        WT[(n4 + 0) * WT_LD + k] = (_Float16)wv.x;
        WT[(n4 + 1) * WT_LD + k] = (_Float16)wv.y;
        WT[(n4 + 2) * WT_LD + k] = (_Float16)wv.z;
        WT[(n4 + 3) * WT_LD + k] = (_Float16)wv.w;
    }

    const int am = lane & 15, ag = lane >> 4;

    float asv[8], adv[8];
    if (as_out) {
#pragma unroll
        for (int n0 = 0; n0 < 8; ++n0) {
            asv[n0] = att_s[n0 * 16 + am];
            adv[n0] = att_d[n0 * 16 + am];
        }
    }

    const int ntiles = (nrows + 63) >> 6;
    for (int tile = blockIdx.x; tile < ntiles; tile += gridDim.x) {
        const int rbase = tile * 64;
        __syncthreads();
        {
            const int r = t >> 2;
            const int c0 = (t & 3) * 32;      // halfs
            const int gr = rbase + r;
            _Float16 tmp[32];
            if (gr < nrows) {
                const float* src = X + (size_t)gr * 128 + c0;
#pragma unroll
                for (int q = 0; q < 8; ++q) {
                    const float4 v = *reinterpret_cast<const float4*>(src + q * 4);
                    tmp[q * 4 + 0] = (_Float16)v.x; tmp[q * 4 + 1] = (_Float16)v.y;
                    tmp[q * 4 + 2] = (_Float16)v.z; tmp[q * 4 + 3] = (_Float16)v.w;
                }
            } else {
#pragma unroll
                for (int q = 0; q < 32; ++q) tmp[q] = (_Float16)0.f;
            }
#pragma unroll
            for (int q = 0; q < 4; ++q)
                *reinterpret_cast<f16x8*>(&At[r * WT_LD + c0 + q * 8]) =
                    *reinterpret_cast<const f16x8*>(&tmp[q * 8]);
        }
        __syncthreads();

        const int srow = wid * 16;
        f16x8 a[4];
#pragma unroll
        for (int kb = 0; kb < 4; ++kb)
            a[kb] = *reinterpret_cast<const f16x8*>(
                &At[(srow + am) * WT_LD + kb * 32 + ag * 8]);

        f32x4 acc[8];
#pragma unroll
        for (int n0 = 0; n0 < 8; ++n0) {
            f32x4 c = {0.f, 0.f, 0.f, 0.f};
#pragma unroll
            for (int kb = 0; kb < 4; ++kb) {
                const f16x8 b = *reinterpret_cast<const f16x8*>(
                    &WT[(n0 * 16 + am) * WT_LD + kb * 32 + ag * 8]);
                c = __builtin_amdgcn_mfma_f32_16x16x32_f16(a[kb], b, c, 0, 0, 0);
            }
            acc[n0] = c;
        }

        const int growbase = rbase + srow + ag * 4;

#pragma unroll
        for (int j = 0; j < 4; ++j) {
            const int grow = growbase + j;
            if (grow < nrows) {
#pragma unroll
                for (int n0 = 0; n0 < 8; ++n0)
                    Y[(size_t)grow * 128 + n0 * 16 + am] = (_Float16)acc[n0][j];
            }
        }

        if (as_out) {
#pragma unroll
            for (int j = 0; j < 4; ++j) {
                float s0 = 0.f, s1 = 0.f, d0 = 0.f, d1 = 0.f;
#pragma unroll
                for (int n0 = 0; n0 < 4; ++n0) {
                    s0 = fmaf(acc[n0][j], asv[n0], s0);
                    d0 = fmaf(acc[n0][j], adv[n0], d0);
                }
#pragma unroll
                for (int n0 = 4; n0 < 8; ++n0) {
                    s1 = fmaf(acc[n0][j], asv[n0], s1);
                    d1 = fmaf(acc[n0][j], adv[n0], d1);
                }
#pragma unroll
                for (int off = 1; off < 16; off <<= 1) {
                    s0 += __shfl_xor(s0, off, 64); s1 += __shfl_xor(s1, off, 64);
                    d0 += __shfl_xor(d0, off, 64); d1 += __shfl_xor(d1, off, 64);
                }
                const int grow = growbase + j;
                if (am == 0 && grow < nrows) {
                    as_out[grow] = make_float2(s0, s1);
                    ad_out[grow] = make_float2(d0, d1);
                }
            }
        }
    }
}

// ---------------- CSR build ----------------
__global__ __launch_bounds__(256) void init_counts_k(int* __restrict__ counts, int N)
{
    const int i = blockIdx.x * blockDim.x + threadIdx.x;
    if (i < N) counts[i] = 1;   // self-loop pre-counted
}

__global__ __launch_bounds__(256) void hist_xcd_k(
    const int* __restrict__ edst, int E, int* __restrict__ counts, int npp)
{
    const int part = blockIdx.x & 7;
    const int lo = part * npp;
    const int hiN = lo + npp;
    const int bi = blockIdx.x >> 3;
    const int stride = (gridDim.x >> 3) * blockDim.x;
    for (int e = bi * blockDim.x + threadIdx.x; e < E; e += stride) {
        const int d = edst[e];
        if (d >= lo && d < hiN) atomicAdd(&counts[d], 1);
    }
}

__global__ __launch_bounds__(256) void scan_phase1(
    const int* __restrict__ counts, int* __restrict__ blockSums, int N)
{
    __shared__ int wsum[4];
    const int b = blockIdx.x, t = threadIdx.x;
    const int base = b * 1024 + t * 4;
    int s = 0;
    if (base + 3 < N) {
        const int4 c = *reinterpret_cast<const int4*>(&counts[base]);
        s = c.x + c.y + c.z + c.w;
    } else {
#pragma unroll
        for (int k = 0; k < 4; ++k) if (base + k < N) s += counts[base + k];
    }
#pragma unroll
    for (int off = 32; off; off >>= 1) s += __shfl_xor(s, off, 64);
    if ((t & 63) == 0) wsum[t >> 6] = s;
    __syncthreads();
    if (t == 0) blockSums[b] = wsum[0] + wsum[1] + wsum[2] + wsum[3];
}

__global__ __launch_bounds__(256) void scan_phase2(
    int* __restrict__ blockSums, int nb, int* __restrict__ row_ptr, int N)
{
    __shared__ int wsum[4];
    __shared__ int carry_sh;
    const int t = threadIdx.x;
    if (t == 0) carry_sh = 0;
    __syncthreads();
    for (int base = 0; base < nb; base += 256) {
        const int i = base + t;
        const int v = (i < nb) ? blockSums[i] : 0;
        int x = v;
#pragma unroll
        for (int off = 1; off < 64; off <<= 1) {
            const int y = __shfl_up(x, off, 64);
            if ((t & 63) >= off) x += y;
        }
        if ((t & 63) == 63) wsum[t >> 6] = x;
        __syncthreads();
        int woff = 0;
        for (int w = 0; w < (t >> 6); ++w) woff += wsum[w];
        const int carry = carry_sh;
        if (i < nb) blockSums[i] = carry + woff + x - v;
        __syncthreads();
        if (t == 255) carry_sh = carry + woff + x;
        __syncthreads();
    }
    if (t == 0) row_ptr[N] = carry_sh;
}

__global__ __launch_bounds__(256) void scan_phase3(
    const int* __restrict__ counts, const int* __restrict__ blockSums,
    int* __restrict__ row_ptr, int N)
{
    __shared__ int wsum[4];
    const int b = blockIdx.x, t = threadIdx.x;
    const int base = b * 1024 + t * 4;
    int v0 = 0, v1 = 0, v2 = 0, v3 = 0;
    if (base + 3 < N) {
        const int4 c = *reinterpret_cast<const int4*>(&counts[base]);
        v0 = c.x; v1 = c.y; v2 = c.z; v3 = c.w;
    } else {
        if (base + 0 < N) v0 = counts[base + 0];
        if (base + 1 < N) v1 = counts[base + 1];
        if (base + 2 < N) v2 = counts[base + 2];
        if (base + 3 < N) v3 = counts[base + 3];
    }
    const int tsum = v0 + v1 + v2 + v3;
    int x = tsum;
#pragma unroll
    for (int off = 1; off < 64; off <<= 1) {
        const int y = __shfl_up(x, off, 64);
        if ((t & 63) >= off) x += y;
    }
    if ((t & 63) == 63) wsum[t >> 6] = x;
    __syncthreads();
    int woff = 0;
    for (int w = 0; w < (t >> 6); ++w) woff += wsum[w];
    int excl = blockSums[b] + woff + x - tsum;
    if (base + 0 < N) row_ptr[base + 0] = excl;
    if (base + 1 < N) row_ptr[base + 1] = excl + v0;
    if (base + 2 < N) row_ptr[base + 2] = excl + v0 + v1;
    if (base + 3 < N) row_ptr[base + 3] = excl + v0 + v1 + v2;
}

__global__ __launch_bounds__(256) void init_cursor_k(
    const int* __restrict__ row_ptr, int* __restrict__ cursor,
    int* __restrict__ csr_src, int N)
{
    const int i = blockIdx.x * blockDim.x + threadIdx.x;
    if (i < N) {
        const int p = row_ptr[i];
        csr_src[p] = i;
        cursor[i] = p + 1;
    }
}

__global__ __launch_bounds__(256) void scatter_xcd_k(
    const int* __restrict__ esrc, const int* __restrict__ edst, int E,
    int* __restrict__ cursor, int* __restrict__ csr_src, int npp)
{
    const int part = blockIdx.x & 7;
    const int lo = part * npp;
    const int hiN = lo + npp;
    const int bi = blockIdx.x >> 3;
    const int stride = (gridDim.x >> 3) * blockDim.x;
    for (int e = bi * blockDim.x + threadIdx.x; e < E; e += stride) {
        const int d = edst[e];
        if (d >= lo && d < hiN) {
            const int pos = atomicAdd(&cursor[d], 1);
            csr_src[pos] = esrc[e];
        }
    }
}

// ---------------- CSR aggregation: one wave per node, 2 edges/wave-step ----------------
// Lanes 0-31 handle edge j, lanes 32-63 edge j+1; lane owns channels 4*l32..4*l32+3
// (8B gather per lane). Halves combined at the end via shfl_xor(32).
__global__ __launch_bounds__(256) void csr_aggregate(
    const int* __restrict__ row_ptr, const int* __restrict__ csr_src,
    const unsigned* __restrict__ h2u, const float2* __restrict__ as_,
    const float2* __restrict__ ad_, const float* __restrict__ bias,
    float* __restrict__ out, int N, int do_relu)
{
    const int lane = threadIdx.x & 63;
    const int node = (blockIdx.x * blockDim.x + threadIdx.x) >> 6;
    if (node >= N) return;
    const int l32 = lane & 31;
    const int half = lane >> 5;
    const bool head1 = l32 >= 16;      // channels 4*l32 >= 64

    const int start = row_ptr[node];
    const int end   = row_ptr[node + 1];
    const float2 ad = ad_[node];

    float den0 = 0.f, den1 = 0.f;
    float acc0 = 0.f, acc1 = 0.f, acc2 = 0.f, acc3 = 0.f;

    for (int base = start; base < end; base += 64) {
        const int cnt = min(64, end - base);
        float ex0 = 0.f, ex1 = 0.f;
        int s = 0;
        if (lane < cnt) {
            s = csr_src[base + lane];
            const float2 as = as_[s];
            float e0 = as.x + ad.x; e0 = fmaxf(e0, 0.2f * e0);   // leaky relu
            float e1 = as.y + ad.y; e1 = fmaxf(e1, 0.2f * e1);
            ex0 = __expf(e0); ex1 = __expf(e1);
            den0 += ex0; den1 += ex1;
        }
        int j = 0;
        for (; j + 8 <= cnt; j += 8) {      // 4 pairs = 8 edges, 4 loads in flight
            uint2 hv[4]; float e[4];
#pragma unroll
            for (int q = 0; q < 4; ++q) {
                const int jA = j + 2 * q, jB = jA + 1;
                const int sA = __builtin_amdgcn_readlane(s, jA);
                const int sB = __builtin_amdgcn_readlane(s, jB);
                const float eA = head1 ? rl_f(ex1, jA) : rl_f(ex0, jA);
                const float eB = head1 ? rl_f(ex1, jB) : rl_f(ex0, jB);
                e[q] = half ? eB : eA;
                const int src = half ? sB : sA;
                hv[q] = *reinterpret_cast<const uint2*>(
                    h2u + (unsigned)(src * 64 + l32 * 2));
            }
#pragma unroll
            for (int q = 0; q < 4; ++q) {
                fma_mix_lo(acc0, hv[q].x, e[q]);
                fma_mix_hi(acc1, hv[q].x, e[q]);
                fma_mix_lo(acc2, hv[q].y, e[q]);
                fma_mix_hi(acc3, hv[q].y, e[q]);
            }
        }
        for (; j < cnt; j += 2) {           // tail pairs (odd cnt zero-padded)
            const int jA = j, jB = j + 1;
            const int sA = __builtin_amdgcn_readlane(s, jA);
            const int sB = __builtin_amdgcn_readlane(s, jB);
            const float eA = head1 ? rl_f(ex1, jA) : rl_f(ex0, jA);
            const float eB = head1 ? rl_f(ex1, jB) : rl_f(ex0, jB);
            const float e = half ? eB : eA;
            const int src = half ? sB : sA;
            const uint2 hv = *reinterpret_cast<const uint2*>(
                h2u + (unsigned)(src * 64 + l32 * 2));
            fma_mix_lo(acc0, hv.x, e);
            fma_mix_hi(acc1, hv.x, e);
            fma_mix_lo(acc2, hv.y, e);
            fma_mix_hi(acc3, hv.y, e);
        }
    }

    // combine the two edge-halves (same channels, disjoint edge subsets)
    acc0 += __shfl_xor(acc0, 32, 64);
    acc1 += __shfl_xor(acc1, 32, 64);
    acc2 += __shfl_xor(acc2, 32, 64);
    acc3 += __shfl_xor(acc3, 32, 64);

#pragma unroll
    for (int off = 32; off; off >>= 1) {
        den0 += __shfl_xor(den0, off, 64);
        den1 += __shfl_xor(den1, off, 64);
    }

    if (half == 0) {
        const float rd = 1.f / (head1 ? den1 : den0);
        const float4 bv = *reinterpret_cast<const float4*>(&bias[l32 * 4]);
        float4 v;
        v.x = fmaf(acc0, rd, bv.x);
        v.y = fmaf(acc1, rd, bv.y);
        v.z = fmaf(acc2, rd, bv.z);
        v.w = fmaf(acc3, rd, bv.w);
        if (do_relu) {
            v.x = fmaxf(v.x, 0.f); v.y = fmaxf(v.y, 0.f);
            v.z = fmaxf(v.z, 0.f); v.w = fmaxf(v.w, 0.f);
        }
        *reinterpret_cast<float4*>(&out[(size_t)node * 128 + l32 * 4]) = v;
    }
}

// ---------------- build rearranged decoder weight: Wuv[128][128] ----------------
__global__ void build_wuv(const float* __restrict__ lin1_w, float* __restrict__ Wuv)
{
    const int i = blockIdx.x * blockDim.x + threadIdx.x;
    if (i >= 128 * 128) return;
    const int k = i >> 7, j = i & 127;
    Wuv[i] = (j < 64) ? lin1_w[k * 64 + j] : lin1_w[(128 + k) * 64 + (j - 64)];
}

// ---------------- decoder: TWO label edges per wave (dword gathers) ----------------
// Lanes 0-31: edge 2*pid; lanes 32-63: edge 2*pid+1. Lane handles channels 2*l32,2*l32+1.
__global__ __launch_bounds__(256) void decode_k(
    const int* __restrict__ eli, int L_, const unsigned* __restrict__ uvd,
    const float* __restrict__ lin1_b, const float* __restrict__ lin2_w,
    const float* __restrict__ lin2_b, float* __restrict__ out)
{
    const int lane = threadIdx.x & 63;
    const int l32 = lane & 31;
    const int half = lane >> 5;
    const int pstride = (gridDim.x * blockDim.x) >> 6;
    const float2 bv = ((const float2*)lin1_b)[l32];
    const float2 wv = ((const float2*)lin2_w)[l32];
    const float b2 = lin2_b[0];
    const int npairs = (L_ + 1) >> 1;
    for (int pid = (blockIdx.x * blockDim.x + threadIdx.x) >> 6; pid < npairs; pid += pstride) {
        const int w = min(pid * 2 + half, L_ - 1);
        const int a = eli[w], b = eli[L_ + w];
        const unsigned ua = uvd[(unsigned)(a * 64 + l32)];        // u halfs 2l32, 2l32+1
        const unsigned vb = uvd[(unsigned)(b * 64 + 32 + l32)];   // v halfs 64+2l32, +1
        float x0 = bv.x, x1 = bv.y;
        asm("v_fma_mix_f32 %0, %1, 1.0, %0 op_sel_hi:[1,0,0]" : "+v"(x0) : "v"(ua));
        asm("v_fma_mix_f32 %0, %1, 1.0, %0 op_sel:[1,0,0] op_sel_hi:[1,0,0]" : "+v"(x1) : "v"(ua));
        asm("v_fma_mix_f32 %0, %1, 1.0, %0 op_sel_hi:[1,0,0]" : "+v"(x0) : "v"(vb));
        asm("v_fma_mix_f32 %0, %1, 1.0, %0 op_sel:[1,0,0] op_sel_hi:[1,0,0]" : "+v"(x1) : "v"(vb));
        x0 = fmaxf(x0, 0.f); x1 = fmaxf(x1, 0.f);
        float p = fmaf(x0, wv.x, x1 * wv.y);
#pragma unroll
        for (int off = 1; off < 32; off <<= 1) p += __shfl_xor(p, off, 64);
        if (l32 == 0 && pid * 2 + half < L_) out[pid * 2 + half] = p + b2;
    }
}

extern "C" void kernel_launch(void* const* d_in, const int* in_sizes, int n_in,
                              void* d_out, int out_size, void* d_ws, size_t ws_size,
                              hipStream_t stream)
{
    const float* x     = (const float*)d_in[0];
    const int*   ei    = (const int*)d_in[1];
    const int*   eli   = (const int*)d_in[2];
    const float* W1    = (const float*)d_in[3];
    const float* atts1 = (const float*)d_in[4];
    const float* attd1 = (const float*)d_in[5];
    const float* bias1 = (const float*)d_in[6];
    const float* W2    = (const float*)d_in[7];
    const float* atts2 = (const float*)d_in[8];
    const float* attd2 = (const float*)d_in[9];
    const float* bias2 = (const float*)d_in[10];
    const float* lin1w = (const float*)d_in[11];
    const float* lin1b = (const float*)d_in[12];
    const float* lin2w = (const float*)d_in[13];
    const float* lin2b = (const float*)d_in[14];
    float* out = (float*)d_out;

    const int N = in_sizes[0] / 128;
    const int E = in_sizes[1] / 2;
    const int L = in_sizes[2] / 2;

    float* ws   = (float*)d_ws;
    __half2* h16 = (__half2*)ws;                  // N*64 half2 = N*128 halfs
    float* x2z  = ws + (size_t)N * 64;            // N*128
    float* a_s  = x2z + (size_t)N * 128;          // N*2
    float* a_d  = a_s + (size_t)N * 2;            // N*2
    float* Wuv  = a_d + (size_t)N * 2;            // 128*128
    int* row_ptr = (int*)(Wuv + 128 * 128);       // N+1 (padded to N+4)
    int* counts  = row_ptr + (N + 4);             // N (16B-aligned)
    int* cursor  = counts + N;                    // N
    int* csr_src = cursor + N;                    // E+N
    int* blockSums = csr_src + (E + N);           // nb

    const int nBlocks256 = (N + 255) / 256;
    const int nb = (N + 1023) / 1024;
    const int npp = (N + 7) / 8;
    const int ntiles = (N + 63) / 64;
    const int gemmGrid = ntiles < 768 ? ntiles : 768;

    // ---- CSR build (once, reused by both layers) ----
    init_counts_k<<<nBlocks256, 256, 0, stream>>>(counts, N);
    hist_xcd_k<<<2048, 256, 0, stream>>>(ei + E, E, counts, npp);
    scan_phase1<<<nb, 256, 0, stream>>>(counts, blockSums, N);
    scan_phase2<<<1, 256, 0, stream>>>(blockSums, nb, row_ptr, N);
    scan_phase3<<<nb, 256, 0, stream>>>(counts, blockSums, row_ptr, N);
    init_cursor_k<<<nBlocks256, 256, 0, stream>>>(row_ptr, cursor, csr_src, N);
    scatter_xcd_k<<<2048, 256, 0, stream>>>(ei, ei + E, E, cursor, csr_src, npp);

    for (int layer = 0; layer < 2; ++layer) {
        const float* xin  = (layer == 0) ? x : x2z;
        const float* W    = (layer == 0) ? W1 : W2;
        const float* as_w = (layer == 0) ? atts1 : atts2;
        const float* ad_w = (layer == 0) ? attd1 : attd2;
        const float* bs   = (layer == 0) ? bias1 : bias2;

        gemm_mfma<<<gemmGrid, 256, 0, stream>>>(xin, W, (_Float16*)h16, N, as_w, ad_w,
                                                (float2*)a_s, (float2*)a_d);
        csr_aggregate<<<(N + 3) / 4, 256, 0, stream>>>(row_ptr, csr_src,
                                                       (const unsigned*)h16,
                                                       (const float2*)a_s, (const float2*)a_d,
                                                       bs, x2z, N, (layer == 0) ? 1 : 0);
    }

    build_wuv<<<64, 256, 0, stream>>>(lin1w, Wuv);
    gemm_mfma<<<gemmGrid, 256, 0, stream>>>(x2z, Wuv, (_Float16*)h16, N,
                                            nullptr, nullptr, nullptr, nullptr);
    decode_k<<<8192, 256, 0, stream>>>(eli, L, (const unsigned*)h16,
                                       lin1b, lin2w, lin2b, out);
}

// Round 12
// 430.952 us; speedup vs baseline: 1.0841x; 1.0163x over previous
//
#include <hip/hip_runtime.h>
#include <hip/hip_fp16.h>

// GNN link predict: 2-layer GAT (H=2, C=64, HC=128) + factored MLP decoder.
// GEMMs via v_mfma_f32_16x16x32_f16 (fp16 in, fp32 accum) with fused attn coefs
// and register-prefetch double-buffered staging.
// fp16 gather tables; CSR built once; XCD-partitioned hist+scatter.
// csr_aggregate: 2 edges/wave, 8B/lane gathers (at random-gather roofline).

typedef _Float16 f16x8 __attribute__((ext_vector_type(8)));
typedef float f32x4 __attribute__((ext_vector_type(4)));

__device__ __forceinline__ float rl_f(float v, int lane) {
    return __int_as_float(__builtin_amdgcn_readlane(__float_as_int(v), lane));
}

// acc += (f32)lo_half(hv) * e   /   acc += (f32)hi_half(hv) * e   (exact cvt + fp32 fma)
__device__ __forceinline__ void fma_mix_lo(float& acc, unsigned hv, float e) {
    asm("v_fma_mix_f32 %0, %1, %2, %0 op_sel_hi:[1,0,0]"
        : "+v"(acc) : "v"(hv), "v"(e));
}
__device__ __forceinline__ void fma_mix_hi(float& acc, unsigned hv, float e) {
    asm("v_fma_mix_f32 %0, %1, %2, %0 op_sel:[1,0,0] op_sel_hi:[1,0,0]"
        : "+v"(acc) : "v"(hv), "v"(e));
}

// ---------------- MFMA GEMM: Y16[nrows,128](fp16) = X[nrows,128]fp32 @ W[128,128]fp32 ----------------
// Reg-prefetch double buffer: tile k+1's X loads issue before tile k's MFMA,
// so global latency hides under compute.
#define WT_LD 136
__global__ __launch_bounds__(256, 3) void gemm_mfma(
    const float* __restrict__ X, const float* __restrict__ W,
    _Float16* __restrict__ Y, int nrows,
    const float* __restrict__ att_s, const float* __restrict__ att_d,
    float2* __restrict__ as_out, float2* __restrict__ ad_out)
{
    __shared__ _Float16 WT[128 * WT_LD];
    __shared__ _Float16 At[64 * WT_LD];
    const int t = threadIdx.x;
    const int lane = t & 63;
    const int wid = t >> 6;

    for (int i = t; i < 128 * 32; i += 256) {
        const int k = i >> 5;
        const int n4 = (i & 31) * 4;
        const float4 wv = *reinterpret_cast<const float4*>(&W[k * 128 + n4]);
        WT[(n4 + 0) * WT_LD + k] = (_Float16)wv.x;
        WT[(n4 + 1) * WT_LD + k] = (_Float16)wv.y;
        WT[(n4 + 2) * WT_LD + k] = (_Float16)wv.z;
        WT[(n4 + 3) * WT_LD + k] = (_Float16)wv.w;
    }

    const int am = lane & 15, ag = lane >> 4;
    const int pr = t >> 2;           // staging row (4 thr/row)
    const int pc = (t & 3) * 32;     // half offset within row (32 halfs = 16 floats x2)

    float asv[8], adv[8];
    if (as_out) {
#pragma unroll
        for (int n0 = 0; n0 < 8; ++n0) {
            asv[n0] = att_s[n0 * 16 + am];
            adv[n0] = att_d[n0 * 16 + am];
        }
    }

    float4 pf[8];
    auto load_pf = [&](int tbase) {
        const int gr = tbase + pr;
        if (gr < nrows) {
            const float* src = X + (size_t)gr * 128 + pc;
#pragma unroll
            for (int q = 0; q < 8; ++q)
                pf[q] = *reinterpret_cast<const float4*>(src + q * 4);
        } else {
#pragma unroll
            for (int q = 0; q < 8; ++q) pf[q] = make_float4(0.f, 0.f, 0.f, 0.f);
        }
    };
    auto write_pf = [&]() {
        _Float16 tmp[32];
#pragma unroll
        for (int q = 0; q < 8; ++q) {
            tmp[q * 4 + 0] = (_Float16)pf[q].x; tmp[q * 4 + 1] = (_Float16)pf[q].y;
            tmp[q * 4 + 2] = (_Float16)pf[q].z; tmp[q * 4 + 3] = (_Float16)pf[q].w;
        }
#pragma unroll
        for (int q = 0; q < 4; ++q)
            *reinterpret_cast<f16x8*>(&At[pr * WT_LD + pc + q * 8]) =
                *reinterpret_cast<const f16x8*>(&tmp[q * 8]);
    };

    const int ntiles = (nrows + 63) >> 6;
    int tile = blockIdx.x;
    if (tile < ntiles) load_pf(tile * 64);

    for (; tile < ntiles; tile += gridDim.x) {
        const int rbase = tile * 64;
        __syncthreads();          // prev tile consumed; first iter fences WT staging
        write_pf();
        __syncthreads();

        const int nt = tile + gridDim.x;
        if (nt < ntiles) load_pf(nt * 64);   // latency hides under MFMA below

        const int srow = wid * 16;
        f16x8 a[4];
#pragma unroll
        for (int kb = 0; kb < 4; ++kb)
            a[kb] = *reinterpret_cast<const f16x8*>(
                &At[(srow + am) * WT_LD + kb * 32 + ag * 8]);

        f32x4 acc[8];
#pragma unroll
        for (int n0 = 0; n0 < 8; ++n0) {
            f32x4 c = {0.f, 0.f, 0.f, 0.f};
#pragma unroll
            for (int kb = 0; kb < 4; ++kb) {
                const f16x8 b = *reinterpret_cast<const f16x8*>(
                    &WT[(n0 * 16 + am) * WT_LD + kb * 32 + ag * 8]);
                c = __builtin_amdgcn_mfma_f32_16x16x32_f16(a[kb], b, c, 0, 0, 0);
            }
            acc[n0] = c;
        }

        const int growbase = rbase + srow + ag * 4;

#pragma unroll
        for (int j = 0; j < 4; ++j) {
            const int grow = growbase + j;
            if (grow < nrows) {
#pragma unroll
                for (int n0 = 0; n0 < 8; ++n0)
                    Y[(size_t)grow * 128 + n0 * 16 + am] = (_Float16)acc[n0][j];
            }
        }

        if (as_out) {
#pragma unroll
            for (int j = 0; j < 4; ++j) {
                float s0 = 0.f, s1 = 0.f, d0 = 0.f, d1 = 0.f;
#pragma unroll
                for (int n0 = 0; n0 < 4; ++n0) {
                    s0 = fmaf(acc[n0][j], asv[n0], s0);
                    d0 = fmaf(acc[n0][j], adv[n0], d0);
                }
#pragma unroll
                for (int n0 = 4; n0 < 8; ++n0) {
                    s1 = fmaf(acc[n0][j], asv[n0], s1);
                    d1 = fmaf(acc[n0][j], adv[n0], d1);
                }
#pragma unroll
                for (int off = 1; off < 16; off <<= 1) {
                    s0 += __shfl_xor(s0, off, 64); s1 += __shfl_xor(s1, off, 64);
                    d0 += __shfl_xor(d0, off, 64); d1 += __shfl_xor(d1, off, 64);
                }
                const int grow = growbase + j;
                if (am == 0 && grow < nrows) {
                    as_out[grow] = make_float2(s0, s1);
                    ad_out[grow] = make_float2(d0, d1);
                }
            }
        }
    }
}

// ---------------- CSR build (counts memset to 0 on host side; +1 folded into scan) ----------------
__global__ __launch_bounds__(256) void hist_xcd_k(
    const int* __restrict__ edst, int E, int* __restrict__ counts, int npp)
{
    const int part = blockIdx.x & 7;
    const int lo = part * npp;
    const int hiN = lo + npp;
    const int bi = blockIdx.x >> 3;
    const int stride = (gridDim.x >> 3) * blockDim.x;
    for (int e = bi * blockDim.x + threadIdx.x; e < E; e += stride) {
        const int d = edst[e];
        if (d >= lo && d < hiN) atomicAdd(&counts[d], 1);
    }
}

// counts[i] holds pure in-degree; effective row length = counts[i] + 1 (self-loop).
__global__ __launch_bounds__(256) void scan_phase1(
    const int* __restrict__ counts, int* __restrict__ blockSums, int N)
{
    __shared__ int wsum[4];
    const int b = blockIdx.x, t = threadIdx.x;
    const int base = b * 1024 + t * 4;
    int s = 0;
    if (base + 3 < N) {
        const int4 c = *reinterpret_cast<const int4*>(&counts[base]);
        s = c.x + c.y + c.z + c.w + 4;
    } else {
#pragma unroll
        for (int k = 0; k < 4; ++k) if (base + k < N) s += counts[base + k] + 1;
    }
#pragma unroll
    for (int off = 32; off; off >>= 1) s += __shfl_xor(s, off, 64);
    if ((t & 63) == 0) wsum[t >> 6] = s;
    __syncthreads();
    if (t == 0) blockSums[b] = wsum[0] + wsum[1] + wsum[2] + wsum[3];
}

__global__ __launch_bounds__(256) void scan_phase2(
    int* __restrict__ blockSums, int nb, int* __restrict__ row_ptr, int N)
{
    __shared__ int wsum[4];
    __shared__ int carry_sh;
    const int t = threadIdx.x;
    if (t == 0) carry_sh = 0;
    __syncthreads();
    for (int base = 0; base < nb; base += 256) {
        const int i = base + t;
        const int v = (i < nb) ? blockSums[i] : 0;
        int x = v;
#pragma unroll
        for (int off = 1; off < 64; off <<= 1) {
            const int y = __shfl_up(x, off, 64);
            if ((t & 63) >= off) x += y;
        }
        if ((t & 63) == 63) wsum[t >> 6] = x;
        __syncthreads();
        int woff = 0;
        for (int w = 0; w < (t >> 6); ++w) woff += wsum[w];
        const int carry = carry_sh;
        if (i < nb) blockSums[i] = carry + woff + x - v;
        __syncthreads();
        if (t == 255) carry_sh = carry + woff + x;
        __syncthreads();
    }
    if (t == 0) row_ptr[N] = carry_sh;
}

// writes row_ptr + cursor + self-loop slot (merged init_cursor)
__global__ __launch_bounds__(256) void scan_phase3(
    const int* __restrict__ counts, const int* __restrict__ blockSums,
    int* __restrict__ row_ptr, int* __restrict__ cursor,
    int* __restrict__ csr_src, int N)
{
    __shared__ int wsum[4];
    const int b = blockIdx.x, t = threadIdx.x;
    const int base = b * 1024 + t * 4;
    int v0 = 0, v1 = 0, v2 = 0, v3 = 0;
    if (base + 3 < N) {
        const int4 c = *reinterpret_cast<const int4*>(&counts[base]);
        v0 = c.x + 1; v1 = c.y + 1; v2 = c.z + 1; v3 = c.w + 1;
    } else {
        if (base + 0 < N) v0 = counts[base + 0] + 1;
        if (base + 1 < N) v1 = counts[base + 1] + 1;
        if (base + 2 < N) v2 = counts[base + 2] + 1;
        if (base + 3 < N) v3 = counts[base + 3] + 1;
    }
    const int tsum = v0 + v1 + v2 + v3;
    int x = tsum;
#pragma unroll
    for (int off = 1; off < 64; off <<= 1) {
        const int y = __shfl_up(x, off, 64);
        if ((t & 63) >= off) x += y;
    }
    if ((t & 63) == 63) wsum[t >> 6] = x;
    __syncthreads();
    int woff = 0;
    for (int w = 0; w < (t >> 6); ++w) woff += wsum[w];
    int excl = blockSums[b] + woff + x - tsum;
    int p = excl;
    if (base + 0 < N) { row_ptr[base + 0] = p; csr_src[p] = base + 0; cursor[base + 0] = p + 1; p += v0; }
    if (base + 1 < N) { row_ptr[base + 1] = p; csr_src[p] = base + 1; cursor[base + 1] = p + 1; p += v1; }
    if (base + 2 < N) { row_ptr[base + 2] = p; csr_src[p] = base + 2; cursor[base + 2] = p + 1; p += v2; }
    if (base + 3 < N) { row_ptr[base + 3] = p; csr_src[p] = base + 3; cursor[base + 3] = p + 1; }
}

__global__ __launch_bounds__(256) void scatter_xcd_k(
    const int* __restrict__ esrc, const int* __restrict__ edst, int E,
    int* __restrict__ cursor, int* __restrict__ csr_src, int npp)
{
    const int part = blockIdx.x & 7;
    const int lo = part * npp;
    const int hiN = lo + npp;
    const int bi = blockIdx.x >> 3;
    const int stride = (gridDim.x >> 3) * blockDim.x;
    for (int e = bi * blockDim.x + threadIdx.x; e < E; e += stride) {
        const int d = edst[e];
        if (d >= lo && d < hiN) {
            const int pos = atomicAdd(&cursor[d], 1);
            csr_src[pos] = esrc[e];
        }
    }
}

// ---------------- CSR aggregation: one wave per node, 2 edges/wave-step ----------------
__global__ __launch_bounds__(256) void csr_aggregate(
    const int* __restrict__ row_ptr, const int* __restrict__ csr_src,
    const unsigned* __restrict__ h2u, const float2* __restrict__ as_,
    const float2* __restrict__ ad_, const float* __restrict__ bias,
    float* __restrict__ out, int N, int do_relu)
{
    const int lane = threadIdx.x & 63;
    const int node = (blockIdx.x * blockDim.x + threadIdx.x) >> 6;
    if (node >= N) return;
    const int l32 = lane & 31;
    const int half = lane >> 5;
    const bool head1 = l32 >= 16;      // channels 4*l32 >= 64

    const int start = row_ptr[node];
    const int end   = row_ptr[node + 1];
    const float2 ad = ad_[node];

    float den0 = 0.f, den1 = 0.f;
    float acc0 = 0.f, acc1 = 0.f, acc2 = 0.f, acc3 = 0.f;

    for (int base = start; base < end; base += 64) {
        const int cnt = min(64, end - base);
        float ex0 = 0.f, ex1 = 0.f;
        int s = 0;
        if (lane < cnt) {
            s = csr_src[base + lane];
            const float2 as = as_[s];
            float e0 = as.x + ad.x; e0 = fmaxf(e0, 0.2f * e0);   // leaky relu
            float e1 = as.y + ad.y; e1 = fmaxf(e1, 0.2f * e1);
            ex0 = __expf(e0); ex1 = __expf(e1);
            den0 += ex0; den1 += ex1;
        }
        int j = 0;
        for (; j + 8 <= cnt; j += 8) {
            uint2 hv[4]; float e[4];
#pragma unroll
            for (int q = 0; q < 4; ++q) {
                const int jA = j + 2 * q, jB = jA + 1;
                const int sA = __builtin_amdgcn_readlane(s, jA);
                const int sB = __builtin_amdgcn_readlane(s, jB);
                const float eA = head1 ? rl_f(ex1, jA) : rl_f(ex0, jA);
                const float eB = head1 ? rl_f(ex1, jB) : rl_f(ex0, jB);
                e[q] = half ? eB : eA;
                const int src = half ? sB : sA;
                hv[q] = *reinterpret_cast<const uint2*>(
                    h2u + (unsigned)(src * 64 + l32 * 2));
            }
#pragma unroll
            for (int q = 0; q < 4; ++q) {
                fma_mix_lo(acc0, hv[q].x, e[q]);
                fma_mix_hi(acc1, hv[q].x, e[q]);
                fma_mix_lo(acc2, hv[q].y, e[q]);
                fma_mix_hi(acc3, hv[q].y, e[q]);
            }
        }
        for (; j < cnt; j += 2) {
            const int jA = j, jB = j + 1;
            const int sA = __builtin_amdgcn_readlane(s, jA);
            const int sB = __builtin_amdgcn_readlane(s, jB);
            const float eA = head1 ? rl_f(ex1, jA) : rl_f(ex0, jA);
            const float eB = head1 ? rl_f(ex1, jB) : rl_f(ex0, jB);
            const float e = half ? eB : eA;
            const int src = half ? sB : sA;
            const uint2 hv = *reinterpret_cast<const uint2*>(
                h2u + (unsigned)(src * 64 + l32 * 2));
            fma_mix_lo(acc0, hv.x, e);
            fma_mix_hi(acc1, hv.x, e);
            fma_mix_lo(acc2, hv.y, e);
            fma_mix_hi(acc3, hv.y, e);
        }
    }

    acc0 += __shfl_xor(acc0, 32, 64);
    acc1 += __shfl_xor(acc1, 32, 64);
    acc2 += __shfl_xor(acc2, 32, 64);
    acc3 += __shfl_xor(acc3, 32, 64);

#pragma unroll
    for (int off = 32; off; off >>= 1) {
        den0 += __shfl_xor(den0, off, 64);
        den1 += __shfl_xor(den1, off, 64);
    }

    if (half == 0) {
        const float rd = 1.f / (head1 ? den1 : den0);
        const float4 bv = *reinterpret_cast<const float4*>(&bias[l32 * 4]);
        float4 v;
        v.x = fmaf(acc0, rd, bv.x);
        v.y = fmaf(acc1, rd, bv.y);
        v.z = fmaf(acc2, rd, bv.z);
        v.w = fmaf(acc3, rd, bv.w);
        if (do_relu) {
            v.x = fmaxf(v.x, 0.f); v.y = fmaxf(v.y, 0.f);
            v.z = fmaxf(v.z, 0.f); v.w = fmaxf(v.w, 0.f);
        }
        *reinterpret_cast<float4*>(&out[(size_t)node * 128 + l32 * 4]) = v;
    }
}

// ---------------- build rearranged decoder weight: Wuv[128][128] ----------------
__global__ void build_wuv(const float* __restrict__ lin1_w, float* __restrict__ Wuv)
{
    const int i = blockIdx.x * blockDim.x + threadIdx.x;
    if (i >= 128 * 128) return;
    const int k = i >> 7, j = i & 127;
    Wuv[i] = (j < 64) ? lin1_w[k * 64 + j] : lin1_w[(128 + k) * 64 + (j - 64)];
}

// ---------------- decoder: TWO label edges per wave (dword gathers) ----------------
__global__ __launch_bounds__(256) void decode_k(
    const int* __restrict__ eli, int L_, const unsigned* __restrict__ uvd,
    const float* __restrict__ lin1_b, const float* __restrict__ lin2_w,
    const float* __restrict__ lin2_b, float* __restrict__ out)
{
    const int lane = threadIdx.x & 63;
    const int l32 = lane & 31;
    const int half = lane >> 5;
    const int pstride = (gridDim.x * blockDim.x) >> 6;
    const float2 bv = ((const float2*)lin1_b)[l32];
    const float2 wv = ((const float2*)lin2_w)[l32];
    const float b2 = lin2_b[0];
    const int npairs = (L_ + 1) >> 1;
    for (int pid = (blockIdx.x * blockDim.x + threadIdx.x) >> 6; pid < npairs; pid += pstride) {
        const int w = min(pid * 2 + half, L_ - 1);
        const int a = eli[w], b = eli[L_ + w];
        const unsigned ua = uvd[(unsigned)(a * 64 + l32)];
        const unsigned vb = uvd[(unsigned)(b * 64 + 32 + l32)];
        float x0 = bv.x, x1 = bv.y;
        asm("v_fma_mix_f32 %0, %1, 1.0, %0 op_sel_hi:[1,0,0]" : "+v"(x0) : "v"(ua));
        asm("v_fma_mix_f32 %0, %1, 1.0, %0 op_sel:[1,0,0] op_sel_hi:[1,0,0]" : "+v"(x1) : "v"(ua));
        asm("v_fma_mix_f32 %0, %1, 1.0, %0 op_sel_hi:[1,0,0]" : "+v"(x0) : "v"(vb));
        asm("v_fma_mix_f32 %0, %1, 1.0, %0 op_sel:[1,0,0] op_sel_hi:[1,0,0]" : "+v"(x1) : "v"(vb));
        x0 = fmaxf(x0, 0.f); x1 = fmaxf(x1, 0.f);
        float p = fmaf(x0, wv.x, x1 * wv.y);
#pragma unroll
        for (int off = 1; off < 32; off <<= 1) p += __shfl_xor(p, off, 64);
        if (l32 == 0 && pid * 2 + half < L_) out[pid * 2 + half] = p + b2;
    }
}

extern "C" void kernel_launch(void* const* d_in, const int* in_sizes, int n_in,
                              void* d_out, int out_size, void* d_ws, size_t ws_size,
                              hipStream_t stream)
{
    const float* x     = (const float*)d_in[0];
    const int*   ei    = (const int*)d_in[1];
    const int*   eli   = (const int*)d_in[2];
    const float* W1    = (const float*)d_in[3];
    const float* atts1 = (const float*)d_in[4];
    const float* attd1 = (const float*)d_in[5];
    const float* bias1 = (const float*)d_in[6];
    const float* W2    = (const float*)d_in[7];
    const float* atts2 = (const float*)d_in[8];
    const float* attd2 = (const float*)d_in[9];
    const float* bias2 = (const float*)d_in[10];
    const float* lin1w = (const float*)d_in[11];
    const float* lin1b = (const float*)d_in[12];
    const float* lin2w = (const float*)d_in[13];
    const float* lin2b = (const float*)d_in[14];
    float* out = (float*)d_out;

    const int N = in_sizes[0] / 128;
    const int E = in_sizes[1] / 2;
    const int L = in_sizes[2] / 2;

    float* ws   = (float*)d_ws;
    __half2* h16 = (__half2*)ws;                  // N*64 half2 = N*128 halfs
    float* x2z  = ws + (size_t)N * 64;            // N*128
    float* a_s  = x2z + (size_t)N * 128;          // N*2
    float* a_d  = a_s + (size_t)N * 2;            // N*2
    float* Wuv  = a_d + (size_t)N * 2;            // 128*128
    int* row_ptr = (int*)(Wuv + 128 * 128);       // N+1 (padded to N+4)
    int* counts  = row_ptr + (N + 4);             // N (16B-aligned)
    int* cursor  = counts + N;                    // N
    int* csr_src = cursor + N;                    // E+N
    int* blockSums = csr_src + (E + N);           // nb

    const int nb = (N + 1023) / 1024;
    const int npp = (N + 7) / 8;
    const int ntiles = (N + 63) / 64;
    const int gemmGrid = ntiles < 768 ? ntiles : 768;

    // ---- CSR build (once, reused by both layers) ----
    hipMemsetAsync(counts, 0, (size_t)N * sizeof(int), stream);
    hist_xcd_k<<<2048, 256, 0, stream>>>(ei + E, E, counts, npp);
    scan_phase1<<<nb, 256, 0, stream>>>(counts, blockSums, N);
    scan_phase2<<<1, 256, 0, stream>>>(blockSums, nb, row_ptr, N);
    scan_phase3<<<nb, 256, 0, stream>>>(counts, blockSums, row_ptr, cursor, csr_src, N);
    scatter_xcd_k<<<2048, 256, 0, stream>>>(ei, ei + E, E, cursor, csr_src, npp);

    for (int layer = 0; layer < 2; ++layer) {
        const float* xin  = (layer == 0) ? x : x2z;
        const float* W    = (layer == 0) ? W1 : W2;
        const float* as_w = (layer == 0) ? atts1 : atts2;
        const float* ad_w = (layer == 0) ? attd1 : attd2;
        const float* bs   = (layer == 0) ? bias1 : bias2;

        gemm_mfma<<<gemmGrid, 256, 0, stream>>>(xin, W, (_Float16*)h16, N, as_w, ad_w,
                                                (float2*)a_s, (float2*)a_d);
        csr_aggregate<<<(N + 3) / 4, 256, 0, stream>>>(row_ptr, csr_src,
                                                       (const unsigned*)h16,
                                                       (const float2*)a_s, (const float2*)a_d,
                                                       bs, x2z, N, (layer == 0) ? 1 : 0);
    }

    build_wuv<<<64, 256, 0, stream>>>(lin1w, Wuv);
    gemm_mfma<<<gemmGrid, 256, 0, stream>>>(x2z, Wuv, (_Float16*)h16, N,
                                            nullptr, nullptr, nullptr, nullptr);
    decode_k<<<8192, 256, 0, stream>>>(eli, L, (const unsigned*)h16,
                                       lin1b, lin2w, lin2b, out);
}

// Round 13
// 417.837 us; speedup vs baseline: 1.1182x; 1.0314x over previous
//
#include <hip/hip_runtime.h>
#include <hip/hip_fp16.h>

// GNN link predict: 2-layer GAT (H=2, C=64, HC=128) + factored MLP decoder.
// GEMMs via v_mfma_f32_16x16x32_f16 (fp16 in, fp32 accum), fused attn coefs,
// reg-prefetch double-buffered staging, template fp32/fp16 input.
// All inter-layer tensors fp16 (bit-identical to fp32 store + fp16 stage-cvt).
// CSR built once; plain hist + XCD-partitioned scatter.
// csr_aggregate: 2 edges/wave, 8B/lane gathers (at random-gather roofline).

typedef _Float16 f16x8 __attribute__((ext_vector_type(8)));
typedef float f32x4 __attribute__((ext_vector_type(4)));

__device__ __forceinline__ float rl_f(float v, int lane) {
    return __int_as_float(__builtin_amdgcn_readlane(__float_as_int(v), lane));
}

// acc += (f32)lo_half(hv) * e   /   acc += (f32)hi_half(hv) * e   (exact cvt + fp32 fma)
__device__ __forceinline__ void fma_mix_lo(float& acc, unsigned hv, float e) {
    asm("v_fma_mix_f32 %0, %1, %2, %0 op_sel_hi:[1,0,0]"
        : "+v"(acc) : "v"(hv), "v"(e));
}
__device__ __forceinline__ void fma_mix_hi(float& acc, unsigned hv, float e) {
    asm("v_fma_mix_f32 %0, %1, %2, %0 op_sel:[1,0,0] op_sel_hi:[1,0,0]"
        : "+v"(acc) : "v"(hv), "v"(e));
}

// ---------------- MFMA GEMM: Y16[nrows,128](fp16) = X[nrows,128] @ W[128,128]fp32 ----------------
// FP16IN: input rows are fp16 (direct 16B staging loads); else fp32 (cvt during stage).
#define WT_LD 136
template<bool FP16IN>
__global__ __launch_bounds__(256, 3) void gemm_mfma(
    const void* __restrict__ Xv, const float* __restrict__ W,
    _Float16* __restrict__ Y, int nrows,
    const float* __restrict__ att_s, const float* __restrict__ att_d,
    float2* __restrict__ as_out, float2* __restrict__ ad_out)
{
    __shared__ _Float16 WT[128 * WT_LD];
    __shared__ _Float16 At[64 * WT_LD];
    const int t = threadIdx.x;
    const int lane = t & 63;
    const int wid = t >> 6;

    for (int i = t; i < 128 * 32; i += 256) {
        const int k = i >> 5;
        const int n4 = (i & 31) * 4;
        const float4 wv = *reinterpret_cast<const float4*>(&W[k * 128 + n4]);
        WT[(n4 + 0) * WT_LD + k] = (_Float16)wv.x;
        WT[(n4 + 1) * WT_LD + k] = (_Float16)wv.y;
        WT[(n4 + 2) * WT_LD + k] = (_Float16)wv.z;
        WT[(n4 + 3) * WT_LD + k] = (_Float16)wv.w;
    }

    const int am = lane & 15, ag = lane >> 4;
    const int pr = t >> 2;           // staging row (4 thr/row)
    const int pc = (t & 3) * 32;     // element offset within row (32 elems/thread)

    float asv[8], adv[8];
    if (as_out) {
#pragma unroll
        for (int n0 = 0; n0 < 8; ++n0) {
            asv[n0] = att_s[n0 * 16 + am];
            adv[n0] = att_d[n0 * 16 + am];
        }
    }

    float4 pff[8];   // fp32 path prefetch
    uint4  pfh[4];   // fp16 path prefetch (32 halfs = 64B)
    auto load_pf = [&](int tbase) {
        const int gr = tbase + pr;
        if (FP16IN) {
            if (gr < nrows) {
                const uint4* src = reinterpret_cast<const uint4*>(
                    (const _Float16*)Xv + (size_t)gr * 128 + pc);
#pragma unroll
                for (int q = 0; q < 4; ++q) pfh[q] = src[q];
            } else {
#pragma unroll
                for (int q = 0; q < 4; ++q) pfh[q] = make_uint4(0, 0, 0, 0);
            }
        } else {
            if (gr < nrows) {
                const float* src = (const float*)Xv + (size_t)gr * 128 + pc;
#pragma unroll
                for (int q = 0; q < 8; ++q)
                    pff[q] = *reinterpret_cast<const float4*>(src + q * 4);
            } else {
#pragma unroll
                for (int q = 0; q < 8; ++q) pff[q] = make_float4(0.f, 0.f, 0.f, 0.f);
            }
        }
    };
    auto write_pf = [&]() {
        if (FP16IN) {
#pragma unroll
            for (int q = 0; q < 4; ++q)
                *reinterpret_cast<uint4*>(&At[pr * WT_LD + pc + q * 8]) = pfh[q];
        } else {
            _Float16 tmp[32];
#pragma unroll
            for (int q = 0; q < 8; ++q) {
                tmp[q * 4 + 0] = (_Float16)pff[q].x; tmp[q * 4 + 1] = (_Float16)pff[q].y;
                tmp[q * 4 + 2] = (_Float16)pff[q].z; tmp[q * 4 + 3] = (_Float16)pff[q].w;
            }
#pragma unroll
            for (int q = 0; q < 4; ++q)
                *reinterpret_cast<f16x8*>(&At[pr * WT_LD + pc + q * 8]) =
                    *reinterpret_cast<const f16x8*>(&tmp[q * 8]);
        }
    };

    const int ntiles = (nrows + 63) >> 6;
    int tile = blockIdx.x;
    if (tile < ntiles) load_pf(tile * 64);

    for (; tile < ntiles; tile += gridDim.x) {
        const int rbase = tile * 64;
        __syncthreads();          // prev tile consumed; first iter fences WT staging
        write_pf();
        __syncthreads();

        const int nt = tile + gridDim.x;
        if (nt < ntiles) load_pf(nt * 64);   // latency hides under MFMA below

        const int srow = wid * 16;
        f16x8 a[4];
#pragma unroll
        for (int kb = 0; kb < 4; ++kb)
            a[kb] = *reinterpret_cast<const f16x8*>(
                &At[(srow + am) * WT_LD + kb * 32 + ag * 8]);

        f32x4 acc[8];
#pragma unroll
        for (int n0 = 0; n0 < 8; ++n0) {
            f32x4 c = {0.f, 0.f, 0.f, 0.f};
#pragma unroll
            for (int kb = 0; kb < 4; ++kb) {
                const f16x8 b = *reinterpret_cast<const f16x8*>(
                    &WT[(n0 * 16 + am) * WT_LD + kb * 32 + ag * 8]);
                c = __builtin_amdgcn_mfma_f32_16x16x32_f16(a[kb], b, c, 0, 0, 0);
            }
            acc[n0] = c;
        }

        const int growbase = rbase + srow + ag * 4;

#pragma unroll
        for (int j = 0; j < 4; ++j) {
            const int grow = growbase + j;
            if (grow < nrows) {
#pragma unroll
                for (int n0 = 0; n0 < 8; ++n0)
                    Y[(size_t)grow * 128 + n0 * 16 + am] = (_Float16)acc[n0][j];
            }
        }

        if (as_out) {
#pragma unroll
            for (int j = 0; j < 4; ++j) {
                float s0 = 0.f, s1 = 0.f, d0 = 0.f, d1 = 0.f;
#pragma unroll
                for (int n0 = 0; n0 < 4; ++n0) {
                    s0 = fmaf(acc[n0][j], asv[n0], s0);
                    d0 = fmaf(acc[n0][j], adv[n0], d0);
                }
#pragma unroll
                for (int n0 = 4; n0 < 8; ++n0) {
                    s1 = fmaf(acc[n0][j], asv[n0], s1);
                    d1 = fmaf(acc[n0][j], adv[n0], d1);
                }
#pragma unroll
                for (int off = 1; off < 16; off <<= 1) {
                    s0 += __shfl_xor(s0, off, 64); s1 += __shfl_xor(s1, off, 64);
                    d0 += __shfl_xor(d0, off, 64); d1 += __shfl_xor(d1, off, 64);
                }
                const int grow = growbase + j;
                if (am == 0 && grow < nrows) {
                    as_out[grow] = make_float2(s0, s1);
                    ad_out[grow] = make_float2(d0, d1);
                }
            }
        }
    }
}

// ---------------- CSR build ----------------
// plain single-pass hist (partitioned replay was neutral-to-negative: atomics
// don't write-amplify like plain stores; 8x edge re-read was pure overhead).
__global__ __launch_bounds__(256) void hist_k(
    const int* __restrict__ edst, int E, int* __restrict__ counts)
{
    const int stride = gridDim.x * blockDim.x;
    for (int e = blockIdx.x * blockDim.x + threadIdx.x; e < E; e += stride)
        atomicAdd(&counts[edst[e]], 1);
}

// counts[i] holds pure in-degree; effective row length = counts[i] + 1 (self-loop).
__global__ __launch_bounds__(256) void scan_phase1(
    const int* __restrict__ counts, int* __restrict__ blockSums, int N)
{
    __shared__ int wsum[4];
    const int b = blockIdx.x, t = threadIdx.x;
    const int base = b * 1024 + t * 4;
    int s = 0;
    if (base + 3 < N) {
        const int4 c = *reinterpret_cast<const int4*>(&counts[base]);
        s = c.x + c.y + c.z + c.w + 4;
    } else {
#pragma unroll
        for (int k = 0; k < 4; ++k) if (base + k < N) s += counts[base + k] + 1;
    }
#pragma unroll
    for (int off = 32; off; off >>= 1) s += __shfl_xor(s, off, 64);
    if ((t & 63) == 0) wsum[t >> 6] = s;
    __syncthreads();
    if (t == 0) blockSums[b] = wsum[0] + wsum[1] + wsum[2] + wsum[3];
}

__global__ __launch_bounds__(256) void scan_phase2(
    int* __restrict__ blockSums, int nb, int* __restrict__ row_ptr, int N)
{
    __shared__ int wsum[4];
    __shared__ int carry_sh;
    const int t = threadIdx.x;
    if (t == 0) carry_sh = 0;
    __syncthreads();
    for (int base = 0; base < nb; base += 256) {
        const int i = base + t;
        const int v = (i < nb) ? blockSums[i] : 0;
        int x = v;
#pragma unroll
        for (int off = 1; off < 64; off <<= 1) {
            const int y = __shfl_up(x, off, 64);
            if ((t & 63) >= off) x += y;
        }
        if ((t & 63) == 63) wsum[t >> 6] = x;
        __syncthreads();
        int woff = 0;
        for (int w = 0; w < (t >> 6); ++w) woff += wsum[w];
        const int carry = carry_sh;
        if (i < nb) blockSums[i] = carry + woff + x - v;
        __syncthreads();
        if (t == 255) carry_sh = carry + woff + x;
        __syncthreads();
    }
    if (t == 0) row_ptr[N] = carry_sh;
}

// writes row_ptr + cursor + self-loop slot
__global__ __launch_bounds__(256) void scan_phase3(
    const int* __restrict__ counts, const int* __restrict__ blockSums,
    int* __restrict__ row_ptr, int* __restrict__ cursor,
    int* __restrict__ csr_src, int N)
{
    __shared__ int wsum[4];
    const int b = blockIdx.x, t = threadIdx.x;
    const int base = b * 1024 + t * 4;
    int v0 = 0, v1 = 0, v2 = 0, v3 = 0;
    if (base + 3 < N) {
        const int4 c = *reinterpret_cast<const int4*>(&counts[base]);
        v0 = c.x + 1; v1 = c.y + 1; v2 = c.z + 1; v3 = c.w + 1;
    } else {
        if (base + 0 < N) v0 = counts[base + 0] + 1;
        if (base + 1 < N) v1 = counts[base + 1] + 1;
        if (base + 2 < N) v2 = counts[base + 2] + 1;
        if (base + 3 < N) v3 = counts[base + 3] + 1;
    }
    const int tsum = v0 + v1 + v2 + v3;
    int x = tsum;
#pragma unroll
    for (int off = 1; off < 64; off <<= 1) {
        const int y = __shfl_up(x, off, 64);
        if ((t & 63) >= off) x += y;
    }
    if ((t & 63) == 63) wsum[t >> 6] = x;
    __syncthreads();
    int woff = 0;
    for (int w = 0; w < (t >> 6); ++w) woff += wsum[w];
    int excl = blockSums[b] + woff + x - tsum;
    int p = excl;
    if (base + 0 < N) { row_ptr[base + 0] = p; csr_src[p] = base + 0; cursor[base + 0] = p + 1; p += v0; }
    if (base + 1 < N) { row_ptr[base + 1] = p; csr_src[p] = base + 1; cursor[base + 1] = p + 1; p += v1; }
    if (base + 2 < N) { row_ptr[base + 2] = p; csr_src[p] = base + 2; cursor[base + 2] = p + 1; p += v2; }
    if (base + 3 < N) { row_ptr[base + 3] = p; csr_src[p] = base + 3; cursor[base + 3] = p + 1; }
}

__global__ __launch_bounds__(256) void scatter_xcd_k(
    const int* __restrict__ esrc, const int* __restrict__ edst, int E,
    int* __restrict__ cursor, int* __restrict__ csr_src, int npp)
{
    const int part = blockIdx.x & 7;
    const int lo = part * npp;
    const int hiN = lo + npp;
    const int bi = blockIdx.x >> 3;
    const int stride = (gridDim.x >> 3) * blockDim.x;
    for (int e = bi * blockDim.x + threadIdx.x; e < E; e += stride) {
        const int d = edst[e];
        if (d >= lo && d < hiN) {
            const int pos = atomicAdd(&cursor[d], 1);
            csr_src[pos] = esrc[e];
        }
    }
}

// ---------------- CSR aggregation: one wave per node, 2 edges/wave-step, fp16 out ----------------
__global__ __launch_bounds__(256) void csr_aggregate(
    const int* __restrict__ row_ptr, const int* __restrict__ csr_src,
    const unsigned* __restrict__ h2u, const float2* __restrict__ as_,
    const float2* __restrict__ ad_, const float* __restrict__ bias,
    uint2* __restrict__ out16, int N, int do_relu)
{
    const int lane = threadIdx.x & 63;
    const int node = (blockIdx.x * blockDim.x + threadIdx.x) >> 6;
    if (node >= N) return;
    const int l32 = lane & 31;
    const int half = lane >> 5;
    const bool head1 = l32 >= 16;      // channels 4*l32 >= 64

    const int start = row_ptr[node];
    const int end   = row_ptr[node + 1];
    const float2 ad = ad_[node];

    float den0 = 0.f, den1 = 0.f;
    float acc0 = 0.f, acc1 = 0.f, acc2 = 0.f, acc3 = 0.f;

    for (int base = start; base < end; base += 64) {
        const int cnt = min(64, end - base);
        float ex0 = 0.f, ex1 = 0.f;
        int s = 0;
        if (lane < cnt) {
            s = csr_src[base + lane];
            const float2 as = as_[s];
            float e0 = as.x + ad.x; e0 = fmaxf(e0, 0.2f * e0);   // leaky relu
            float e1 = as.y + ad.y; e1 = fmaxf(e1, 0.2f * e1);
            ex0 = __expf(e0); ex1 = __expf(e1);
            den0 += ex0; den1 += ex1;
        }
        int j = 0;
        for (; j + 8 <= cnt; j += 8) {
            uint2 hv[4]; float e[4];
#pragma unroll
            for (int q = 0; q < 4; ++q) {
                const int jA = j + 2 * q, jB = jA + 1;
                const int sA = __builtin_amdgcn_readlane(s, jA);
                const int sB = __builtin_amdgcn_readlane(s, jB);
                const float eA = head1 ? rl_f(ex1, jA) : rl_f(ex0, jA);
                const float eB = head1 ? rl_f(ex1, jB) : rl_f(ex0, jB);
                e[q] = half ? eB : eA;
                const int src = half ? sB : sA;
                hv[q] = *reinterpret_cast<const uint2*>(
                    h2u + (unsigned)(src * 64 + l32 * 2));
            }
#pragma unroll
            for (int q = 0; q < 4; ++q) {
                fma_mix_lo(acc0, hv[q].x, e[q]);
                fma_mix_hi(acc1, hv[q].x, e[q]);
                fma_mix_lo(acc2, hv[q].y, e[q]);
                fma_mix_hi(acc3, hv[q].y, e[q]);
            }
        }
        for (; j < cnt; j += 2) {
            const int jA = j, jB = j + 1;
            const int sA = __builtin_amdgcn_readlane(s, jA);
            const int sB = __builtin_amdgcn_readlane(s, jB);
            const float eA = head1 ? rl_f(ex1, jA) : rl_f(ex0, jA);
            const float eB = head1 ? rl_f(ex1, jB) : rl_f(ex0, jB);
            const float e = half ? eB : eA;
            const int src = half ? sB : sA;
            const uint2 hv = *reinterpret_cast<const uint2*>(
                h2u + (unsigned)(src * 64 + l32 * 2));
            fma_mix_lo(acc0, hv.x, e);
            fma_mix_hi(acc1, hv.x, e);
            fma_mix_lo(acc2, hv.y, e);
            fma_mix_hi(acc3, hv.y, e);
        }
    }

    acc0 += __shfl_xor(acc0, 32, 64);
    acc1 += __shfl_xor(acc1, 32, 64);
    acc2 += __shfl_xor(acc2, 32, 64);
    acc3 += __shfl_xor(acc3, 32, 64);

#pragma unroll
    for (int off = 32; off; off >>= 1) {
        den0 += __shfl_xor(den0, off, 64);
        den1 += __shfl_xor(den1, off, 64);
    }

    if (half == 0) {
        const float rd = 1.f / (head1 ? den1 : den0);
        const float4 bv = *reinterpret_cast<const float4*>(&bias[l32 * 4]);
        float vx = fmaf(acc0, rd, bv.x);
        float vy = fmaf(acc1, rd, bv.y);
        float vz = fmaf(acc2, rd, bv.z);
        float vw = fmaf(acc3, rd, bv.w);
        if (do_relu) {
            vx = fmaxf(vx, 0.f); vy = fmaxf(vy, 0.f);
            vz = fmaxf(vz, 0.f); vw = fmaxf(vw, 0.f);
        }
        // fp16 store: bit-identical to fp32 store + fp16 cvt at next gemm's staging
        const __half2 p0 = __float22half2_rn(make_float2(vx, vy));
        const __half2 p1 = __float22half2_rn(make_float2(vz, vw));
        out16[(size_t)node * 32 + l32] =
            make_uint2(*(const unsigned*)&p0, *(const unsigned*)&p1);
    }
}

// ---------------- build rearranged decoder weight: Wuv[128][128] ----------------
__global__ void build_wuv(const float* __restrict__ lin1_w, float* __restrict__ Wuv)
{
    const int i = blockIdx.x * blockDim.x + threadIdx.x;
    if (i >= 128 * 128) return;
    const int k = i >> 7, j = i & 127;
    Wuv[i] = (j < 64) ? lin1_w[k * 64 + j] : lin1_w[(128 + k) * 64 + (j - 64)];
}

// ---------------- decoder: TWO label edges per wave (dword gathers) ----------------
__global__ __launch_bounds__(256) void decode_k(
    const int* __restrict__ eli, int L_, const unsigned* __restrict__ uvd,
    const float* __restrict__ lin1_b, const float* __restrict__ lin2_w,
    const float* __restrict__ lin2_b, float* __restrict__ out)
{
    const int lane = threadIdx.x & 63;
    const int l32 = lane & 31;
    const int half = lane >> 5;
    const int pstride = (gridDim.x * blockDim.x) >> 6;
    const float2 bv = ((const float2*)lin1_b)[l32];
    const float2 wv = ((const float2*)lin2_w)[l32];
    const float b2 = lin2_b[0];
    const int npairs = (L_ + 1) >> 1;
    for (int pid = (blockIdx.x * blockDim.x + threadIdx.x) >> 6; pid < npairs; pid += pstride) {
        const int w = min(pid * 2 + half, L_ - 1);
        const int a = eli[w], b = eli[L_ + w];
        const unsigned ua = uvd[(unsigned)(a * 64 + l32)];
        const unsigned vb = uvd[(unsigned)(b * 64 + 32 + l32)];
        float x0 = bv.x, x1 = bv.y;
        asm("v_fma_mix_f32 %0, %1, 1.0, %0 op_sel_hi:[1,0,0]" : "+v"(x0) : "v"(ua));
        asm("v_fma_mix_f32 %0, %1, 1.0, %0 op_sel:[1,0,0] op_sel_hi:[1,0,0]" : "+v"(x1) : "v"(ua));
        asm("v_fma_mix_f32 %0, %1, 1.0, %0 op_sel_hi:[1,0,0]" : "+v"(x0) : "v"(vb));
        asm("v_fma_mix_f32 %0, %1, 1.0, %0 op_sel:[1,0,0] op_sel_hi:[1,0,0]" : "+v"(x1) : "v"(vb));
        x0 = fmaxf(x0, 0.f); x1 = fmaxf(x1, 0.f);
        float p = fmaf(x0, wv.x, x1 * wv.y);
#pragma unroll
        for (int off = 1; off < 32; off <<= 1) p += __shfl_xor(p, off, 64);
        if (l32 == 0 && pid * 2 + half < L_) out[pid * 2 + half] = p + b2;
    }
}

extern "C" void kernel_launch(void* const* d_in, const int* in_sizes, int n_in,
                              void* d_out, int out_size, void* d_ws, size_t ws_size,
                              hipStream_t stream)
{
    const float* x     = (const float*)d_in[0];
    const int*   ei    = (const int*)d_in[1];
    const int*   eli   = (const int*)d_in[2];
    const float* W1    = (const float*)d_in[3];
    const float* atts1 = (const float*)d_in[4];
    const float* attd1 = (const float*)d_in[5];
    const float* bias1 = (const float*)d_in[6];
    const float* W2    = (const float*)d_in[7];
    const float* atts2 = (const float*)d_in[8];
    const float* attd2 = (const float*)d_in[9];
    const float* bias2 = (const float*)d_in[10];
    const float* lin1w = (const float*)d_in[11];
    const float* lin1b = (const float*)d_in[12];
    const float* lin2w = (const float*)d_in[13];
    const float* lin2b = (const float*)d_in[14];
    float* out = (float*)d_out;

    const int N = in_sizes[0] / 128;
    const int E = in_sizes[1] / 2;
    const int L = in_sizes[2] / 2;

    float* ws   = (float*)d_ws;
    _Float16* h16  = (_Float16*)ws;               // N*128 halfs (N*64 floats)
    _Float16* x2z16 = (_Float16*)(ws + (size_t)N * 64);   // N*128 halfs (x2, then z)
    float* a_s  = ws + (size_t)N * 128;           // N*2
    float* a_d  = a_s + (size_t)N * 2;            // N*2
    float* Wuv  = a_d + (size_t)N * 2;            // 128*128
    int* row_ptr = (int*)(Wuv + 128 * 128);       // N+1 (padded to N+4)
    int* counts  = row_ptr + (N + 4);             // N (16B-aligned)
    int* cursor  = counts + N;                    // N
    int* csr_src = cursor + N;                    // E+N
    int* blockSums = csr_src + (E + N);           // nb

    const int nb = (N + 1023) / 1024;
    const int npp = (N + 7) / 8;
    const int ntiles = (N + 63) / 64;
    const int gemmGrid = ntiles < 768 ? ntiles : 768;

    // ---- CSR build (once, reused by both layers) ----
    hipMemsetAsync(counts, 0, (size_t)N * sizeof(int), stream);
    hist_k<<<2048, 256, 0, stream>>>(ei + E, E, counts);
    scan_phase1<<<nb, 256, 0, stream>>>(counts, blockSums, N);
    scan_phase2<<<1, 256, 0, stream>>>(blockSums, nb, row_ptr, N);
    scan_phase3<<<nb, 256, 0, stream>>>(counts, blockSums, row_ptr, cursor, csr_src, N);
    scatter_xcd_k<<<2048, 256, 0, stream>>>(ei, ei + E, E, cursor, csr_src, npp);

    // ---- layer 1 (fp32 input x) ----
    gemm_mfma<false><<<gemmGrid, 256, 0, stream>>>(x, W1, h16, N, atts1, attd1,
                                                   (float2*)a_s, (float2*)a_d);
    csr_aggregate<<<(N + 3) / 4, 256, 0, stream>>>(row_ptr, csr_src,
                                                   (const unsigned*)h16,
                                                   (const float2*)a_s, (const float2*)a_d,
                                                   bias1, (uint2*)x2z16, N, 1);
    // ---- layer 2 (fp16 input x2) ----
    gemm_mfma<true><<<gemmGrid, 256, 0, stream>>>(x2z16, W2, h16, N, atts2, attd2,
                                                  (float2*)a_s, (float2*)a_d);
    csr_aggregate<<<(N + 3) / 4, 256, 0, stream>>>(row_ptr, csr_src,
                                                   (const unsigned*)h16,
                                                   (const float2*)a_s, (const float2*)a_d,
                                                   bias2, (uint2*)x2z16, N, 0);
    // ---- decoder ----
    build_wuv<<<64, 256, 0, stream>>>(lin1w, Wuv);
    gemm_mfma<true><<<gemmGrid, 256, 0, stream>>>(x2z16, Wuv, h16, N,
                                                  nullptr, nullptr, nullptr, nullptr);
    decode_k<<<8192, 256, 0, stream>>>(eli, L, (const unsigned*)h16,
                                       lin1b, lin2w, lin2b, out);
}